// Round 2
// baseline (506.623 us; speedup 1.0000x reference)
//
#include <hip/hip_runtime.h>

// LSTM: B=4096, T=2048, I=4, H=3, gates i,f,g,o (W rows r = g*3 + u)
// R5: unit-per-lane. 4 lanes per sequence (u = lane&3; u==3 dup replicates
//     unit 2 exactly -- gathered with zero weight). Each lane computes all 4
//     gates of its unit in-lane: removes the gate-broadcast DPP stage, the
//     sigmoid act-fixup fma, and the final o-mul (folded: myh=fma(-2ro,r2,ro))
//     from the serial cycle (~16 -> ~13 stages). One cross-lane stage remains:
//     quad_perm rotations rot1/rot2/rot3 to gather the other units' h.
// R4 lesson: ds_swizzle vs DPP gather was only ~10cy/step -- the ~240cy/step
//     stall is spread across the chain stages; remove stages, not pipes.

#define BB 4096
#define TT 2048
#define L2E 1.4426950408889634f

template<int CTRL>
__device__ __forceinline__ float dppf(float v) {
    return __int_as_float(
        __builtin_amdgcn_update_dpp(0, __float_as_int(v), CTRL, 0xF, 0xF, true));
}

__global__ __launch_bounds__(64, 1) void lstm_seq(
    const float* __restrict__ x, const float* __restrict__ Wih,
    const float* __restrict__ Whh, const float* __restrict__ bih,
    const float* __restrict__ bhh, const int* __restrict__ len,
    float* __restrict__ out)
{
    const int lane = threadIdx.x & 63;
    const int u    = lane & 3;          // unit (3 = dup of unit 2)
    const int j    = lane >> 2;         // sequence within wave (16 per wave)
    const int b    = blockIdx.x * 16 + j;
    const int ur   = (u < 3) ? u : 2;   // weight-row unit

    // Per-gate scale folding: sigmoid gates (i,f,o): -log2e; g gate: +2log2e.
    // cc is carried as 2*log2e*c so tanh(c) = 1 - 2*rcp(1+exp2(cc)).
    float xw[4][4], bias[4], wh[4][4];
    #pragma unroll
    for (int g = 0; g < 4; ++g) {
        const float sc = (g == 2) ? (2.f * L2E) : (-L2E);
        const int r = g * 3 + ur;
        #pragma unroll
        for (int k = 0; k < 4; ++k) xw[g][k] = Wih[r * 4 + k] * sc;
        bias[g] = (bih[r] + bhh[r]) * sc;
        // h slot k arrives via quad rot-k: source unit (u+k)&3; dup-unit weight 0.
        #pragma unroll
        for (int k = 0; k < 4; ++k) {
            const int su = (u + k) & 3;
            wh[g][k] = (su == 3) ? 0.f : Whh[r * 3 + su] * sc;
        }
    }

    const int mylen = len[b];
    int wmax = mylen;
    #pragma unroll
    for (int off = 1; off < 64; off <<= 1)
        wmax = max(wmax, __shfl_xor(wmax, off));
    const int Tloop = (wmax + 7) & ~7;

    float myh = 0.f, cc = 0.f;
    const float4* __restrict__ xrow = ((const float4*)x) + (size_t)b * TT;
    float* __restrict__ orow = out + (size_t)b * (TT * 3);
    const bool writer = (u < 3);

    float4 buf[8];
    float4 xa[8];   // per-step 4-gate x-projection (scale-folded)
    #pragma unroll
    for (int t0 = 0; t0 < 8; ++t0) buf[t0] = xrow[t0];

    for (int tb = 0; tb < Tloop; tb += 8) {
        #pragma unroll
        for (int t0 = 0; t0 < 8; ++t0) {
            const float4 xv = buf[t0];
            xa[t0].x = fmaf(xw[0][3], xv.w, fmaf(xw[0][2], xv.z,
                       fmaf(xw[0][1], xv.y, fmaf(xw[0][0], xv.x, bias[0]))));
            xa[t0].y = fmaf(xw[1][3], xv.w, fmaf(xw[1][2], xv.z,
                       fmaf(xw[1][1], xv.y, fmaf(xw[1][0], xv.x, bias[1]))));
            xa[t0].z = fmaf(xw[2][3], xv.w, fmaf(xw[2][2], xv.z,
                       fmaf(xw[2][1], xv.y, fmaf(xw[2][0], xv.x, bias[2]))));
            xa[t0].w = fmaf(xw[3][3], xv.w, fmaf(xw[3][2], xv.z,
                       fmaf(xw[3][1], xv.y, fmaf(xw[3][0], xv.x, bias[3]))));
        }
        #pragma unroll
        for (int t0 = 0; t0 < 8; ++t0) {
            const int tn = tb + 8 + t0;
            buf[t0] = xrow[tn < TT ? tn : 0];
        }
        #pragma unroll
        for (int t0 = 0; t0 < 8; ++t0) {
            const int t = tb + t0;
            // Gather other units' h: quad_perm rotations (lane u reads u+k mod 4).
            const float h1 = dppf<0x39>(myh);   // rot1: [1,2,3,0]
            const float h2 = dppf<0x4E>(myh);   // rot2: [2,3,0,1]
            const float h3 = dppf<0x93>(myh);   // rot3: [3,0,1,2]
            // Own-h term first (no DPP wait), then the gathered terms.
            float a0 = fmaf(wh[0][0], myh, xa[t0].x);
            float a1 = fmaf(wh[1][0], myh, xa[t0].y);
            float a2 = fmaf(wh[2][0], myh, xa[t0].z);
            float a3 = fmaf(wh[3][0], myh, xa[t0].w);
            a0 = fmaf(wh[0][3], h3, fmaf(wh[0][2], h2, fmaf(wh[0][1], h1, a0)));
            a1 = fmaf(wh[1][3], h3, fmaf(wh[1][2], h2, fmaf(wh[1][1], h1, a1)));
            a2 = fmaf(wh[2][3], h3, fmaf(wh[2][2], h2, fmaf(wh[2][1], h1, a2)));
            a3 = fmaf(wh[3][3], h3, fmaf(wh[3][2], h2, fmaf(wh[3][1], h1, a3)));
            // Gate activations (all in-lane, latency-parallel).
            const float ri = __builtin_amdgcn_rcpf(1.f + __builtin_amdgcn_exp2f(a0));
            const float rf = __builtin_amdgcn_rcpf(1.f + __builtin_amdgcn_exp2f(a1));
            const float rg = __builtin_amdgcn_rcpf(1.f + __builtin_amdgcn_exp2f(a2));
            const float ro = __builtin_amdgcn_rcpf(1.f + __builtin_amdgcn_exp2f(a3));
            // i * (2log2e * tanh(g)); tanh(g) = 1 - 2rg in the folded scale.
            const float gsc = fmaf(-4.f * L2E, rg, 2.f * L2E);
            cc = fmaf(rf, cc, ri * gsc);          // cc = 2log2e * c
            const float r2 = __builtin_amdgcn_rcpf(1.f + __builtin_amdgcn_exp2f(cc));
            myh = fmaf(-2.f * ro, r2, ro);        // o*tanh(c); -2ro forms in trans shadow
            if (writer) orow[t * 3 + u] = (t < mylen) ? myh : 0.f;
        }
    }

    // Zero the remaining tail t in [Tloop, TT) for this wave's 16 rows.
    const int start4 = Tloop * 3 / 4;          // multiple of 6, 16B-aligned
    for (int rr = 0; rr < 16; ++rr) {
        float4* __restrict__ o4 =
            (float4*)(out + ((size_t)(blockIdx.x * 16 + rr)) * (TT * 3));
        for (int idx = start4 + lane; idx < TT * 3 / 4; idx += 64)
            o4[idx] = make_float4(0.f, 0.f, 0.f, 0.f);
    }
}

extern "C" void kernel_launch(void* const* d_in, const int* in_sizes, int n_in,
                              void* d_out, int out_size, void* d_ws, size_t ws_size,
                              hipStream_t stream) {
    const float* x    = (const float*)d_in[0];
    const float* Wih  = (const float*)d_in[1];
    const float* Whh  = (const float*)d_in[2];
    const float* bih  = (const float*)d_in[3];
    const float* bhh  = (const float*)d_in[4];
    const int*   lenp = (const int*)d_in[5];
    float* out = (float*)d_out;

    lstm_seq<<<BB / 16, 64, 0, stream>>>(x, Wih, Whh, bih, bhh, lenp, out);
}

// Round 3
// 407.285 us; speedup vs baseline: 1.2439x; 1.2439x over previous
//
#include <hip/hip_runtime.h>

// LSTM: B=4096, T=2048, I=4, H=3, gates i,f,g,o (W rows r = g*3 + u)
// R6: back to R4 layout (best: 267us; 16 lanes/seq, gate-per-lane, 4 seq/wave).
//     Model from R4/R5: step = chain_stall(~220cy: 4 serial trans + 2 DPP +
//     ~10 VALU stages) + wave issue (~90cy). Shave both:
//       - tree h-dot: p0=fma(wh0,myh,xa) before DPPs; depth after DPP = fma+add
//       - fold o: myh = fma(-2*go, r2, go); -2*go forms in exp2(cc) shadow
//       - store raw myh (finite past len: inf->rcp->0, no NaN), zero [len,TT)
//         in tail; drops per-step cmp+cndmask. s_waitcnt vmcnt(0) orders the
//         same-address store pairs.
// R5 lesson: per-wave ISSUE adds ~1:1 to step time; keep per-lane work minimal.
// R4 lesson: gather pipe choice (LDS vs DPP) ~7cy only; stages matter, pipes don't.

#define BB 4096
#define TT 2048
#define L2E 1.4426950408889634f

template<int CTRL>
__device__ __forceinline__ float dppf(float v) {
    return __int_as_float(
        __builtin_amdgcn_update_dpp(0, __float_as_int(v), CTRL, 0xF, 0xF, true));
}

__global__ __launch_bounds__(64, 1) void lstm_seq(
    const float* __restrict__ x, const float* __restrict__ Wih,
    const float* __restrict__ Whh, const float* __restrict__ bih,
    const float* __restrict__ bhh, const int* __restrict__ len,
    float* __restrict__ out)
{
    const int lane  = threadIdx.x & 63;
    const int s     = lane & 3;          // gate: 0=i,1=f,2=g,3=o
    const int q     = (lane >> 2) & 3;   // quad = unit (3 = dup of unit 2)
    const int row16 = lane >> 4;         // sequence within wave (4 per wave)
    const int b     = blockIdx.x * 4 + row16;
    const int u     = (q < 3) ? q : 2;
    const int wrow  = s * 3 + u;

    // Activation via r = rcp(1+exp2(a)), a = pre*scale:
    //   sigmoid (s!=2): scale=-log2e,  act = r
    //   tanh    (s==2): scale=+2log2e, act = 2L2E - 4L2E*r  (pre-scaled g)
    // Cell carried as cc = 2*log2e*c, so tanh(c) = 1 - 2*rcp(1+exp2(cc)).
    const float scale = (s == 2) ? (2.f * L2E) : (-L2E);
    const float Aa = (s == 2) ? (2.f * L2E) : 0.f;
    const float Bb = (s == 2) ? (-4.f * L2E) : 1.f;

    const float xw0 = Wih[wrow * 4 + 0] * scale;
    const float xw1 = Wih[wrow * 4 + 1] * scale;
    const float xw2 = Wih[wrow * 4 + 2] * scale;
    const float xw3 = Wih[wrow * 4 + 3] * scale;
    const float bias = (bih[wrow] + bhh[wrow]) * scale;

    // h slot j arrives via row_ror:(4j): source quad (q - j) & 3.
    // Zero weight for the dup-quad source.
    float wh[4];
    #pragma unroll
    for (int j = 0; j < 4; ++j) {
        const int srcq = (q - j) & 3;
        wh[j] = (srcq == 3) ? 0.f : Whh[wrow * 3 + srcq] * scale;
    }

    const int mylen = len[b];
    int wmax = mylen;
    #pragma unroll
    for (int off = 1; off < 64; off <<= 1)
        wmax = max(wmax, __shfl_xor(wmax, off));
    const int Tloop = (wmax + 7) & ~7;

    float myh = 0.f, cc = 0.f;
    const float4* __restrict__ xrow = ((const float4*)x) + (size_t)b * TT;
    float* __restrict__ orow = out + (size_t)b * (TT * 3);
    const bool writer = (s == 0) && (q < 3);

    float4 buf[8];
    float xacc[8];
    #pragma unroll
    for (int uu = 0; uu < 8; ++uu) buf[uu] = xrow[uu];

    for (int tb = 0; tb < Tloop; tb += 8) {
        #pragma unroll
        for (int uu = 0; uu < 8; ++uu) {
            const float4 xv = buf[uu];
            xacc[uu] = fmaf(xw3, xv.w, fmaf(xw2, xv.z,
                       fmaf(xw1, xv.y, fmaf(xw0, xv.x, bias))));
        }
        #pragma unroll
        for (int uu = 0; uu < 8; ++uu) {
            const int tn = tb + 8 + uu;
            buf[uu] = xrow[tn < TT ? tn : 0];
        }
        #pragma unroll
        for (int uu = 0; uu < 8; ++uu) {
            const int t = tb + uu;
            // h gather: VALU-pipe DPP row rotates (row = 16 lanes).
            const float h1 = dppf<0x124>(myh);   // row_ror:4  -> quad q-1
            const float h2 = dppf<0x128>(myh);   // row_ror:8  -> quad q-2
            const float h3 = dppf<0x12C>(myh);   // row_ror:12 -> quad q-3
            // Tree: p0 has no DPP dependence; gathered terms pair up.
            const float p0 = fmaf(wh[0], myh, xacc[uu]);
            const float m3 = wh[3] * h3;
            const float p1 = fmaf(wh[1], h1, p0);
            const float p2 = fmaf(wh[2], h2, m3);
            const float a  = p1 + p2;
            const float r = __builtin_amdgcn_rcpf(1.f + __builtin_amdgcn_exp2f(a));
            const float act = fmaf(Bb, r, Aa);
            const float gi = dppf<0x00>(act);   // lane 0 of quad: gate i
            const float gf = dppf<0x55>(act);   // gate f
            const float gg = dppf<0xAA>(act);   // gate g (pre-scaled tanh)
            const float go = dppf<0xFF>(act);   // gate o
            cc = fmaf(gf, cc, gi * gg);         // cc = 2L2E * c
            const float n2go = -2.f * go;       // forms in exp2(cc) shadow
            const float r2 = __builtin_amdgcn_rcpf(1.f + __builtin_amdgcn_exp2f(cc));
            myh = fmaf(n2go, r2, go);           // o * tanh(c)
            if (writer) orow[t * 3 + q] = myh;  // raw; tail zeroes t >= len
        }
    }

    // Order main-loop stores before tail overwrites (same addresses, other lanes).
    asm volatile("s_waitcnt vmcnt(0)" ::: "memory");

    // Zero t in [len[row], TT) for this wave's 4 rows (runs on early-finishing
    // waves; block 0 = longest rows has ~no tail, so no wall-clock cost).
    #pragma unroll
    for (int rr = 0; rr < 4; ++rr) {
        const int bb = blockIdx.x * 4 + rr;
        const int L  = len[bb];
        float* __restrict__ ob = out + (size_t)bb * (TT * 3);
        const int s0 = L * 3;                 // first float to zero
        const int a4 = (s0 + 3) & ~3;         // align up to float4
        if (lane < a4 - s0) ob[s0 + lane] = 0.f;
        float4* __restrict__ o4 = (float4*)ob;
        for (int idx = a4 / 4 + lane; idx < TT * 3 / 4; idx += 64)
            o4[idx] = make_float4(0.f, 0.f, 0.f, 0.f);
    }
}

extern "C" void kernel_launch(void* const* d_in, const int* in_sizes, int n_in,
                              void* d_out, int out_size, void* d_ws, size_t ws_size,
                              hipStream_t stream) {
    const float* x    = (const float*)d_in[0];
    const float* Wih  = (const float*)d_in[1];
    const float* Whh  = (const float*)d_in[2];
    const float* bih  = (const float*)d_in[3];
    const float* bhh  = (const float*)d_in[4];
    const int*   lenp = (const int*)d_in[5];
    float* out = (float*)d_out;

    lstm_seq<<<BB / 4, 64, 0, stream>>>(x, Wih, Whh, bih, bhh, lenp, out);
}